// Round 4
// baseline (219.666 us; speedup 1.0000x reference)
//
#include <hip/hip_runtime.h>
#include <math.h>

// Sizes (fixed by the problem)
#define BATCH 512   // scan sequence length (original batch dim)
#define E     128
#define DI    256
#define S     256
#define DTR   8
#define KCONV 4
#define JWX   520   // dt(8) + B(256) + C(256)

__device__ __forceinline__ float silu_f(float v) {
    return v / (1.0f + __expf(-v));
}

// ---------------------------------------------------------------------------
// kA: heterogeneous fusion of weight transposes (blocks 512..538) and
//     conv2d+lin row-31 projection (blocks 0..511).
// ---------------------------------------------------------------------------
__global__ __launch_bounds__(256) void kA_pre(
    const float* __restrict__ x, const float* __restrict__ conv_w,
    const float* __restrict__ conv_b, const float* __restrict__ lin_w,
    const float* __restrict__ lin_b, float* __restrict__ u31,
    const float* __restrict__ W_in, const float* __restrict__ W_x,
    const float* __restrict__ W_dt, const float* __restrict__ W_out,
    const float* __restrict__ c1w,
    float* __restrict__ W_inT, float* __restrict__ W_xT,
    float* __restrict__ W_dtT, float* __restrict__ W_outT,
    float* __restrict__ c1wT)
{
    const int tid = threadIdx.x;
    if (blockIdx.x >= 512) {
        // ---- transpose part ----
        const int bid = blockIdx.x - 512;
        const float* src; float* dst; int J, K, j0;
        if (bid < 9)       { src = W_x;   dst = W_xT;   J = JWX; K = DI;    j0 = bid * 64; }
        else if (bid < 17) { src = W_in;  dst = W_inT;  J = 512; K = E;     j0 = (bid - 9) * 64; }
        else if (bid < 19) { src = W_out; dst = W_outT; J = E;   K = DI;    j0 = (bid - 17) * 64; }
        else if (bid < 23) { src = W_dt;  dst = W_dtT;  J = DI;  K = DTR;   j0 = (bid - 19) * 64; }
        else               { src = c1w;   dst = c1wT;   J = DI;  K = KCONV; j0 = (bid - 23) * 64; }
        const int j = j0 + (tid & 63);
        if (j >= J) return;
        for (int c = tid >> 6; c < K; c += 4)
            dst[c * J + j] = src[j * K + c];
        return;
    }

    // ---- conv2d + lin row 31 part ----
    const int b = blockIdx.x;
    __shared__ float lw[1024];
    __shared__ float red[10][4];
    __shared__ float Tsh[10];

    const float4 lv = ((const float4*)(lin_w + 31 * 1024))[tid];
    ((float4*)lw)[tid] = lv;
    __syncthreads();

    float acc[10];
#pragma unroll
    for (int k = 0; k < 10; k++) acc[k] = 0.0f;

    const float4 xv = ((const float4*)(x + (size_t)b * 1024))[tid];
    const int p0 = tid * 4;
    const int h = p0 >> 5, w0 = p0 & 31;
    const float xa[4] = {xv.x, xv.y, xv.z, xv.w};
#pragma unroll
    for (int k = 0; k < 4; k++) {
        const float xval = xa[k];
        const int w = w0 + k;
#pragma unroll
        for (int i = 0; i < 3; i++) {
            const int hh = h - (i - 1);
            if (hh < 0 || hh > 31) continue;
#pragma unroll
            for (int j = 0; j < 3; j++) {
                const int ww = w - (j - 1);
                if (ww < 0 || ww > 31) continue;
                acc[i * 3 + j] += xval * lw[hh * 32 + ww];
            }
        }
    }
    acc[9] = lv.x + lv.y + lv.z + lv.w;   // partial sum of lin_w row (SL)

    const int wv = tid >> 6, ln = tid & 63;
#pragma unroll
    for (int k = 0; k < 10; k++) {
#pragma unroll
        for (int m = 1; m < 64; m <<= 1) acc[k] += __shfl_xor(acc[k], m, 64);
    }
    if (ln == 0) {
#pragma unroll
        for (int k = 0; k < 10; k++) red[k][wv] = acc[k];
    }
    __syncthreads();
    if (tid < 10) Tsh[tid] = red[tid][0] + red[tid][1] + red[tid][2] + red[tid][3];
    __syncthreads();

    if (tid < E) {
        const int e = tid;
        float v = lin_b[31] + conv_b[e] * Tsh[9];
#pragma unroll
        for (int k = 0; k < 9; k++) v += conv_w[e * 9 + k] * Tsh[k];
        u31[b * E + e] = v;
    }
}

// ---------------------------------------------------------------------------
// k2: fully fused per-4-rows pipeline:
//   xm rows bb-3..bb+3 (recomputed locally, +37% redundancy) ; zg rows bb..bb+3
//   -> causal conv1d + silu -> xs ; dbl = xs @ W_xT ; delta = softplus(...)
// grid: 128 blocks, 256 threads.
// ---------------------------------------------------------------------------
__global__ __launch_bounds__(256) void k2_fused(
    const float* __restrict__ u31, const float* __restrict__ W_inT,
    const float* __restrict__ c1wT, const float* __restrict__ conv1d_b,
    const float* __restrict__ W_xT, const float* __restrict__ W_dtT,
    const float* __restrict__ b_dt,
    float* __restrict__ zg, float* __restrict__ xs_g,
    float* __restrict__ delta_g, float* __restrict__ Bm, float* __restrict__ Cm)
{
    const int bb = blockIdx.x * 4;
    const int tid = threadIdx.x;
    __shared__ float u[7][E];      // u31 rows bb-3 .. bb+3  (0 if b<0)
    __shared__ float xmL[7][DI];
    __shared__ float xsL[4][DI];
    __shared__ float dt_in[4][8];

    // phase 0: load u31 rows (zeros for b<0)
    for (int idx = tid; idx < 7 * E; idx += 256) {
        const int row = idx / E, e = idx - row * E;
        const int b = bb - 3 + row;
        u[row][e] = (b >= 0) ? u31[b * E + e] : 0.0f;
    }
    __syncthreads();

    // phase 1: xm (7 rows, j = tid < 256) and zg (4 rows, j = 256+tid)
    {
        const int c = tid;
        float xmAcc[7], zgAcc[4];
#pragma unroll
        for (int r = 0; r < 7; r++) xmAcc[r] = 0.0f;
#pragma unroll
        for (int r = 0; r < 4; r++) zgAcc[r] = 0.0f;
#pragma unroll 4
        for (int e = 0; e < E; e++) {
            const float w0 = W_inT[e * 512 + c];
            const float w1 = W_inT[e * 512 + 256 + c];
#pragma unroll
            for (int r = 0; r < 7; r++) xmAcc[r] += w0 * u[r][e];
#pragma unroll
            for (int r = 0; r < 4; r++) zgAcc[r] += w1 * u[3 + r][e];
        }
#pragma unroll
        for (int r = 0; r < 7; r++) xmL[r][c] = xmAcc[r];
#pragma unroll
        for (int r = 0; r < 4; r++) zg[(bb + r) * DI + c] = zgAcc[r];
    }
    __syncthreads();

    // phase 2: causal depthwise conv1d + silu -> xs (rows bb..bb+3)
    for (int idx = tid; idx < 4 * DI; idx += 256) {
        const int r = idx >> 8, c = idx & 255;
        float a = 0.0f;
#pragma unroll
        for (int k = 0; k < KCONV; k++)      // src row = bb+r-3+k -> local r+k
            a += xmL[r + k][c] * c1wT[k * DI + c];
        a += conv1d_b[c];
        const float s = silu_f(a);
        xsL[r][c] = s;
        xs_g[(bb + r) * DI + c] = s;
    }
    __syncthreads();

    // phase 3: dbl = xs @ W_xT ; scatter to dt_in / Bm / Cm
    for (int j = tid; j < JWX; j += 256) {
        float acc[4];
#pragma unroll
        for (int r = 0; r < 4; r++) acc[r] = 0.0f;
#pragma unroll 4
        for (int c = 0; c < DI; c++) {
            const float w = W_xT[c * JWX + j];
#pragma unroll
            for (int r = 0; r < 4; r++) acc[r] += w * xsL[r][c];
        }
#pragma unroll
        for (int r = 0; r < 4; r++) {
            const int b = bb + r;
            if (j < DTR)          dt_in[r][j] = acc[r];
            else if (j < DTR + S) Bm[b * S + (j - DTR)] = acc[r];
            else                  Cm[b * S + (j - DTR - S)] = acc[r];
        }
    }
    __syncthreads();

    // phase 4: delta = softplus(dt_in @ W_dtT + b_dt)
    {
        const int d = tid;
        const float bd = b_dt[d];
#pragma unroll
        for (int r = 0; r < 4; r++) {
            float a = bd;
#pragma unroll
            for (int q = 0; q < DTR; q++) a += dt_in[r][q] * W_dtT[q * DI + d];
            const float sp = (a > 20.0f) ? a : log1pf(__expf(a));
            delta_g[(bb + r) * DI + d] = sp;
        }
    }
}

// ---------------------------------------------------------------------------
// K3 chunked parallel scan.
//   k3a: per-chunk local scan (h_in = 0), writes y_local, hloc, Dchunk
//   k3c: per-(chunk,d) block recomputes its carry from hloc/Dchunk (Horner,
//        bit-identical to a serial carry pass), then adds the fixup to y.
// ---------------------------------------------------------------------------
template <int NCv>
__global__ __launch_bounds__(256) void k3a_local(
    const float* __restrict__ A_log, const float* __restrict__ delta,
    const float* __restrict__ xs, const float* __restrict__ Bm,
    const float* __restrict__ Cm, float* __restrict__ y,
    float* __restrict__ hloc, float* __restrict__ Dchunk)
{
    constexpr int TCv = BATCH / NCv;
    const int tid = threadIdx.x;
    const int wv = tid >> 6, ln = tid & 63;
    const int d = blockIdx.x * 4 + wv;
    const int c = blockIdx.y;
    const int s0 = ln * 4;
    const int t0 = c * TCv;

    const float4 al = *(const float4*)(A_log + d * S + s0);
    float4 A;
    A.x = -__expf(al.x); A.y = -__expf(al.y);
    A.z = -__expf(al.z); A.w = -__expf(al.w);

    float4 h = make_float4(0.f, 0.f, 0.f, 0.f);
    float cd = 0.0f;
    float pr[8];

    for (int tb = 0; tb < TCv; tb += 8) {
#pragma unroll
        for (int i = 0; i < 8; i++) {
            const int tt = t0 + tb + i;
            const float dd = delta[tt * DI + d];
            cd += dd;
            const float u = dd * xs[tt * DI + d];
            const float4 B = *(const float4*)(Bm + tt * S + s0);
            const float4 C = *(const float4*)(Cm + tt * S + s0);
            h.x = __expf(dd * A.x) * h.x + u * B.x;
            h.y = __expf(dd * A.y) * h.y + u * B.y;
            h.z = __expf(dd * A.z) * h.z + u * B.z;
            h.w = __expf(dd * A.w) * h.w + u * B.w;
            pr[i] = h.x * C.x + h.y * C.y + h.z * C.z + h.w * C.w;
        }
#pragma unroll
        for (int i = 0; i < 8; i++) {
#pragma unroll
            for (int m = 1; m < 64; m <<= 1) pr[i] += __shfl_xor(pr[i], m, 64);
        }
        if (ln == 0) {
#pragma unroll
            for (int i = 0; i < 8; i++) y[(t0 + tb + i) * DI + d] = pr[i];
        }
    }

    *(float4*)(hloc + ((size_t)(c * DI + d)) * S + s0) = h;
    if (ln == 0) Dchunk[c * DI + d] = cd;
}

template <int NCv>
__global__ __launch_bounds__(256) void k3c_fix(
    const float* __restrict__ A_log, const float* __restrict__ delta,
    const float* __restrict__ Cm, const float* __restrict__ hloc,
    const float* __restrict__ Dchunk, float* __restrict__ y)
{
    constexpr int TCv = BATCH / NCv;
    const int tid = threadIdx.x;
    const int wv = tid >> 6, ln = tid & 63;
    const int d = blockIdx.x * 4 + wv;
    const int c = blockIdx.y + 1;
    const int s0 = ln * 4;
    const int t0 = c * TCv;

    const float4 al = *(const float4*)(A_log + d * S + s0);
    float4 A;
    A.x = -__expf(al.x); A.y = -__expf(al.y);
    A.z = -__expf(al.z); A.w = -__expf(al.w);

    // carry: hin[c] via the serial recurrence h = hloc[cp-1] + exp(A*D[cp-1])*h
    float4 hi = make_float4(0.f, 0.f, 0.f, 0.f);
    for (int cp = 1; cp <= c; cp++) {
        const float4 hl = *(const float4*)(hloc + ((size_t)((cp - 1) * DI + d)) * S + s0);
        const float Dc = Dchunk[(cp - 1) * DI + d];
        hi.x = hl.x + __expf(A.x * Dc) * hi.x;
        hi.y = hl.y + __expf(A.y * Dc) * hi.y;
        hi.z = hl.z + __expf(A.z * Dc) * hi.z;
        hi.w = hl.w + __expf(A.w * Dc) * hi.w;
    }

    float cd = 0.0f;
    float pr[8];

    for (int tb = 0; tb < TCv; tb += 8) {
#pragma unroll
        for (int i = 0; i < 8; i++) {
            const int tt = t0 + tb + i;
            const float dd = delta[tt * DI + d];
            cd += dd;
            const float4 C = *(const float4*)(Cm + tt * S + s0);
            const float fx = hi.x * __expf(cd * A.x);
            const float fy = hi.y * __expf(cd * A.y);
            const float fz = hi.z * __expf(cd * A.z);
            const float fw = hi.w * __expf(cd * A.w);
            pr[i] = fx * C.x + fy * C.y + fz * C.z + fw * C.w;
        }
#pragma unroll
        for (int i = 0; i < 8; i++) {
#pragma unroll
            for (int m = 1; m < 64; m <<= 1) pr[i] += __shfl_xor(pr[i], m, 64);
        }
        if (ln == 0) {
#pragma unroll
            for (int i = 0; i < 8; i++) {
                const int tt = t0 + tb + i;
                y[tt * DI + d] += pr[i];
            }
        }
    }
}

// ---------------------------------------------------------------------------
// K4: yf = (y + xs*Dp)*silu(zg); feat = yf @ W_outT; 3 head matmuls -> d_out
// ---------------------------------------------------------------------------
__global__ __launch_bounds__(256) void k4_heads(
    const float* __restrict__ y, const float* __restrict__ xs,
    const float* __restrict__ Dp, const float* __restrict__ zg,
    const float* __restrict__ W_outT,
    const float* __restrict__ We, const float* __restrict__ be,
    const float* __restrict__ Wa, const float* __restrict__ ba,
    const float* __restrict__ Wq, const float* __restrict__ bq,
    float* __restrict__ out)
{
    const int bb = blockIdx.x * 2;
    const int tid = threadIdx.x;
    __shared__ float yf[2][DI];
    __shared__ float feat[2][E];

    for (int idx = tid; idx < 2 * DI; idx += 256) {
        const int r = idx >> 8, c = idx & 255;
        const int b = bb + r;
        const float z = zg[b * DI + c];
        yf[r][c] = (y[b * DI + c] + xs[b * DI + c] * Dp[c]) * silu_f(z);
    }
    __syncthreads();

    {
        const int r = tid >> 7, e = tid & 127;
        float a = 0.0f;
#pragma unroll 8
        for (int dd = 0; dd < DI; dd++) a += yf[r][dd] * W_outT[dd * E + e];
        feat[r][e] = a;
    }
    __syncthreads();

    if (tid < 16) {
        const int r = tid >> 3, hd = tid & 7;
        const int b = bb + r;
        const float* wrow;
        float bias;
        int dst;
        if (hd == 0)      { wrow = We;                 bias = be[0];      dst = b; }
        else if (hd < 4)  { wrow = Wa + (hd - 1) * E;  bias = ba[hd - 1]; dst = 512 + b * 3 + (hd - 1); }
        else              { wrow = Wq + (hd - 4) * E;  bias = bq[hd - 4]; dst = 2048 + b * 4 + (hd - 4); }
        float a = bias;
#pragma unroll 4
        for (int e = 0; e < E; e++) a += feat[r][e] * wrow[e];
        out[dst] = a;
    }
}

// ---------------------------------------------------------------------------
template <int NCv>
static void launch_scan(const float* A_log, const float* delta, const float* xs,
                        const float* Bm, const float* Cm, float* y,
                        float* hloc, float* Dchunk, hipStream_t stream)
{
    k3a_local<NCv><<<dim3(64, NCv), 256, 0, stream>>>(A_log, delta, xs, Bm, Cm, y, hloc, Dchunk);
    k3c_fix<NCv><<<dim3(64, NCv - 1), 256, 0, stream>>>(A_log, delta, Cm, hloc, Dchunk, y);
}

extern "C" void kernel_launch(void* const* d_in, const int* in_sizes, int n_in,
                              void* d_out, int out_size, void* d_ws, size_t ws_size,
                              hipStream_t stream)
{
    const float* x        = (const float*)d_in[0];
    const float* conv_w   = (const float*)d_in[1];
    const float* conv_b   = (const float*)d_in[2];
    const float* lin_w    = (const float*)d_in[3];
    const float* lin_b    = (const float*)d_in[4];
    const float* W_in     = (const float*)d_in[5];
    const float* conv1d_w = (const float*)d_in[6];
    const float* conv1d_b = (const float*)d_in[7];
    const float* W_x      = (const float*)d_in[8];
    const float* W_dt     = (const float*)d_in[9];
    const float* b_dt     = (const float*)d_in[10];
    const float* A_log    = (const float*)d_in[11];
    const float* Dp       = (const float*)d_in[12];
    const float* W_out    = (const float*)d_in[13];
    const float* We       = (const float*)d_in[14];
    const float* be       = (const float*)d_in[15];
    const float* Wa       = (const float*)d_in[16];
    const float* ba       = (const float*)d_in[17];
    const float* Wq       = (const float*)d_in[18];
    const float* bq       = (const float*)d_in[19];
    float* out = (float*)d_out;

    float* ws = (float*)d_ws;
    float* u31    = ws;                    // 512*128
    float* zg     = u31    + 512 * 128;    // 512*256 each below
    float* xs     = zg     + 512 * 256;
    float* delta  = xs     + 512 * 256;
    float* Bm     = delta  + 512 * 256;
    float* Cm     = Bm     + 512 * 256;
    float* y      = Cm     + 512 * 256;
    float* W_inT  = y      + 512 * 256;    // 128*512
    float* W_xT   = W_inT  + 128 * 512;    // 256*520
    float* W_dtT  = W_xT   + 256 * JWX;    // 8*256
    float* W_outT = W_dtT  + 8 * 256;      // 256*128
    float* c1wT   = W_outT + 256 * 128;    // 4*256
    float* tail   = c1wT   + 4 * 256;      // hloc / Dchunk

    const size_t base_floats = (size_t)(tail - ws);
    const size_t avail = ws_size / 4 - base_floats;

    kA_pre<<<539, 256, 0, stream>>>(x, conv_w, conv_b, lin_w, lin_b, u31,
                                    W_in, W_x, W_dt, W_out, conv1d_w,
                                    W_inT, W_xT, W_dtT, W_outT, c1wT);
    k2_fused<<<128, 256, 0, stream>>>(u31, W_inT, c1wT, conv1d_b, W_xT, W_dtT, b_dt,
                                      zg, xs, delta, Bm, Cm);

    // need: NC*DI*S + NC*DI floats for hloc + Dchunk
    if (avail >= (size_t)32 * DI * S + 32 * DI) {
        float* hloc = tail;
        float* Dch  = hloc + (size_t)32 * DI * S;
        launch_scan<32>(A_log, delta, xs, Bm, Cm, y, hloc, Dch, stream);
    } else if (avail >= (size_t)16 * DI * S + 16 * DI) {
        float* hloc = tail;
        float* Dch  = hloc + (size_t)16 * DI * S;
        launch_scan<16>(A_log, delta, xs, Bm, Cm, y, hloc, Dch, stream);
    } else {
        float* hloc = tail;
        float* Dch  = hloc + (size_t)8 * DI * S;
        launch_scan<8>(A_log, delta, xs, Bm, Cm, y, hloc, Dch, stream);
    }

    k4_heads<<<256, 256, 0, stream>>>(y, xs, Dp, zg, W_outT, We, be, Wa, ba, Wq, bq, out);
}

// Round 5
// 180.376 us; speedup vs baseline: 1.2178x; 1.2178x over previous
//
#include <hip/hip_runtime.h>
#include <math.h>

// Sizes (fixed by the problem)
#define BATCH 512   // scan sequence length (original batch dim)
#define E     128
#define DI    256
#define S     256
#define DTR   8
#define KCONV 4
#define JWX   520   // dt(8) + B(256) + C(256)

__device__ __forceinline__ float silu_f(float v) {
    return v / (1.0f + __expf(-v));
}

// ---------------------------------------------------------------------------
// kA: heterogeneous fusion of weight transposes (blocks 512..538) and
//     conv2d+lin row-31 projection (blocks 0..511).
// ---------------------------------------------------------------------------
__global__ __launch_bounds__(256) void kA_pre(
    const float* __restrict__ x, const float* __restrict__ conv_w,
    const float* __restrict__ conv_b, const float* __restrict__ lin_w,
    const float* __restrict__ lin_b, float* __restrict__ u31,
    const float* __restrict__ W_in, const float* __restrict__ W_x,
    const float* __restrict__ W_dt, const float* __restrict__ W_out,
    const float* __restrict__ c1w,
    float* __restrict__ W_inT, float* __restrict__ W_xT,
    float* __restrict__ W_dtT, float* __restrict__ W_outT,
    float* __restrict__ c1wT)
{
    const int tid = threadIdx.x;
    if (blockIdx.x >= 512) {
        // ---- transpose part ----
        const int bid = blockIdx.x - 512;
        const float* src; float* dst; int J, K, j0;
        if (bid < 9)       { src = W_x;   dst = W_xT;   J = JWX; K = DI;    j0 = bid * 64; }
        else if (bid < 17) { src = W_in;  dst = W_inT;  J = 512; K = E;     j0 = (bid - 9) * 64; }
        else if (bid < 19) { src = W_out; dst = W_outT; J = E;   K = DI;    j0 = (bid - 17) * 64; }
        else if (bid < 23) { src = W_dt;  dst = W_dtT;  J = DI;  K = DTR;   j0 = (bid - 19) * 64; }
        else               { src = c1w;   dst = c1wT;   J = DI;  K = KCONV; j0 = (bid - 23) * 64; }
        const int j = j0 + (tid & 63);
        if (j >= J) return;
        for (int c = tid >> 6; c < K; c += 4)
            dst[c * J + j] = src[j * K + c];
        return;
    }

    // ---- conv2d + lin row 31 part ----
    const int b = blockIdx.x;
    __shared__ float lw[1024];
    __shared__ float red[10][4];
    __shared__ float Tsh[10];

    const float4 lv = ((const float4*)(lin_w + 31 * 1024))[tid];
    ((float4*)lw)[tid] = lv;
    __syncthreads();

    float acc[10];
#pragma unroll
    for (int k = 0; k < 10; k++) acc[k] = 0.0f;

    const float4 xv = ((const float4*)(x + (size_t)b * 1024))[tid];
    const int p0 = tid * 4;
    const int h = p0 >> 5, w0 = p0 & 31;
    const float xa[4] = {xv.x, xv.y, xv.z, xv.w};
#pragma unroll
    for (int k = 0; k < 4; k++) {
        const float xval = xa[k];
        const int w = w0 + k;
#pragma unroll
        for (int i = 0; i < 3; i++) {
            const int hh = h - (i - 1);
            if (hh < 0 || hh > 31) continue;
#pragma unroll
            for (int j = 0; j < 3; j++) {
                const int ww = w - (j - 1);
                if (ww < 0 || ww > 31) continue;
                acc[i * 3 + j] += xval * lw[hh * 32 + ww];
            }
        }
    }
    acc[9] = lv.x + lv.y + lv.z + lv.w;   // partial sum of lin_w row (SL)

    const int wv = tid >> 6, ln = tid & 63;
#pragma unroll
    for (int k = 0; k < 10; k++) {
#pragma unroll
        for (int m = 1; m < 64; m <<= 1) acc[k] += __shfl_xor(acc[k], m, 64);
    }
    if (ln == 0) {
#pragma unroll
        for (int k = 0; k < 10; k++) red[k][wv] = acc[k];
    }
    __syncthreads();
    if (tid < 10) Tsh[tid] = red[tid][0] + red[tid][1] + red[tid][2] + red[tid][3];
    __syncthreads();

    if (tid < E) {
        const int e = tid;
        float v = lin_b[31] + conv_b[e] * Tsh[9];
#pragma unroll
        for (int k = 0; k < 9; k++) v += conv_w[e * 9 + k] * Tsh[k];
        u31[b * E + e] = v;
    }
}

// ---------------------------------------------------------------------------
// K2a: xz[b,j] = sum_e u31[b,e]*W_inT[e,j]. Tile 4b x 64j, 1 output/thread.
// grid (128, 8) = 1024 blocks. Wave = one b-row, lanes on consecutive j.
// ---------------------------------------------------------------------------
__global__ __launch_bounds__(256) void k2a_win(
    const float* __restrict__ u31, const float* __restrict__ W_inT,
    float* __restrict__ xm, float* __restrict__ zg)
{
    const int bb = blockIdx.x * 4;
    const int tid = threadIdx.x;
    __shared__ float u[4][E];
    for (int i = tid; i < 4 * E; i += 256) u[i >> 7][i & 127] = u31[bb * E + i];
    __syncthreads();

    const int r = tid >> 6;
    const int j = blockIdx.y * 64 + (tid & 63);
    float a = 0.0f;
#pragma unroll 8
    for (int e = 0; e < E; e++) a += u[r][e] * W_inT[e * 512 + j];
    if (j < 256) xm[(bb + r) * DI + j] = a;
    else         zg[(bb + r) * DI + (j - 256)] = a;
}

// ---------------------------------------------------------------------------
// K2b: causal depthwise conv1d(K=4)+silu -> xs; dbl = xs @ W_x.T (via W_xT);
//      delta = softplus(dbl[:, :8] @ W_dt.T + b_dt); Bm/Cm split.
// Tile 4b x 64j, grid (128, 9). jgroup 0 also does xs_g write + delta.
// ---------------------------------------------------------------------------
__global__ __launch_bounds__(256) void k2b_conv_wx(
    const float* __restrict__ xm, const float* __restrict__ c1wT,
    const float* __restrict__ conv1d_b, const float* __restrict__ W_xT,
    const float* __restrict__ W_dtT, const float* __restrict__ b_dt,
    float* __restrict__ xs_g, float* __restrict__ delta_g,
    float* __restrict__ Bm, float* __restrict__ Cm)
{
    const int bb = blockIdx.x * 4;
    const int g = blockIdx.y;
    const int tid = threadIdx.x;
    __shared__ float xs[4][DI];
    __shared__ float dtin[4][8];

    // phase A: xs = silu(causal_conv1d(xm) + bias); coalesced
    for (int idx = tid; idx < 4 * DI; idx += 256) {
        const int r = idx >> 8, c = idx & 255;
        const int b = bb + r;
        float a = 0.0f;
#pragma unroll
        for (int k = 0; k < KCONV; k++) {
            const int src = b - 3 + k;
            if (src >= 0) a += xm[src * DI + c] * c1wT[k * DI + c];
        }
        a += conv1d_b[c];
        const float s = silu_f(a);
        xs[r][c] = s;
        if (g == 0) xs_g[b * DI + c] = s;
    }
    __syncthreads();

    // phase B: 1 output/thread; wave-uniform xs broadcast, coalesced W_xT
    const int r = tid >> 6;
    const int j = g * 64 + (tid & 63);
    if (j < JWX) {
        float a = 0.0f;
#pragma unroll 8
        for (int c = 0; c < DI; c++) a += xs[r][c] * W_xT[c * JWX + j];
        const int b = bb + r;
        if (j < DTR)          dtin[r][j] = a;
        else if (j < DTR + S) Bm[b * S + (j - DTR)] = a;
        else                  Cm[b * S + (j - DTR - S)] = a;
    }
    __syncthreads();

    // phase C: delta = softplus(dtin @ W_dt.T + b_dt) (jgroup 0 only)
    if (g == 0) {
        const int d = tid;
        const float bd = b_dt[d];
#pragma unroll
        for (int r2 = 0; r2 < 4; r2++) {
            float a = bd;
#pragma unroll
            for (int q = 0; q < DTR; q++) a += dtin[r2][q] * W_dtT[q * DI + d];
            const float sp = (a > 20.0f) ? a : log1pf(__expf(a));
            delta_g[(bb + r2) * DI + d] = sp;
        }
    }
}

// ---------------------------------------------------------------------------
// K3 chunked parallel scan.
//   k3a: per-chunk local scan (h_in = 0), writes y_local, hloc, Dchunk
//   k3c: per-(chunk,d) block recomputes its carry from hloc/Dchunk (Horner,
//        bit-identical to a serial carry pass), then adds the fixup to y.
// ---------------------------------------------------------------------------
template <int NCv>
__global__ __launch_bounds__(256) void k3a_local(
    const float* __restrict__ A_log, const float* __restrict__ delta,
    const float* __restrict__ xs, const float* __restrict__ Bm,
    const float* __restrict__ Cm, float* __restrict__ y,
    float* __restrict__ hloc, float* __restrict__ Dchunk)
{
    constexpr int TCv = BATCH / NCv;
    const int tid = threadIdx.x;
    const int wv = tid >> 6, ln = tid & 63;
    const int d = blockIdx.x * 4 + wv;
    const int c = blockIdx.y;
    const int s0 = ln * 4;
    const int t0 = c * TCv;

    const float4 al = *(const float4*)(A_log + d * S + s0);
    float4 A;
    A.x = -__expf(al.x); A.y = -__expf(al.y);
    A.z = -__expf(al.z); A.w = -__expf(al.w);

    float4 h = make_float4(0.f, 0.f, 0.f, 0.f);
    float cd = 0.0f;
    float pr[8];

    for (int tb = 0; tb < TCv; tb += 8) {
#pragma unroll
        for (int i = 0; i < 8; i++) {
            const int tt = t0 + tb + i;
            const float dd = delta[tt * DI + d];
            cd += dd;
            const float u = dd * xs[tt * DI + d];
            const float4 B = *(const float4*)(Bm + tt * S + s0);
            const float4 C = *(const float4*)(Cm + tt * S + s0);
            h.x = __expf(dd * A.x) * h.x + u * B.x;
            h.y = __expf(dd * A.y) * h.y + u * B.y;
            h.z = __expf(dd * A.z) * h.z + u * B.z;
            h.w = __expf(dd * A.w) * h.w + u * B.w;
            pr[i] = h.x * C.x + h.y * C.y + h.z * C.z + h.w * C.w;
        }
#pragma unroll
        for (int i = 0; i < 8; i++) {
#pragma unroll
            for (int m = 1; m < 64; m <<= 1) pr[i] += __shfl_xor(pr[i], m, 64);
        }
        if (ln == 0) {
#pragma unroll
            for (int i = 0; i < 8; i++) y[(t0 + tb + i) * DI + d] = pr[i];
        }
    }

    *(float4*)(hloc + ((size_t)(c * DI + d)) * S + s0) = h;
    if (ln == 0) Dchunk[c * DI + d] = cd;
}

template <int NCv>
__global__ __launch_bounds__(256) void k3c_fix(
    const float* __restrict__ A_log, const float* __restrict__ delta,
    const float* __restrict__ Cm, const float* __restrict__ hloc,
    const float* __restrict__ Dchunk, float* __restrict__ y)
{
    constexpr int TCv = BATCH / NCv;
    const int tid = threadIdx.x;
    const int wv = tid >> 6, ln = tid & 63;
    const int d = blockIdx.x * 4 + wv;
    const int c = blockIdx.y + 1;
    const int s0 = ln * 4;
    const int t0 = c * TCv;

    const float4 al = *(const float4*)(A_log + d * S + s0);
    float4 A;
    A.x = -__expf(al.x); A.y = -__expf(al.y);
    A.z = -__expf(al.z); A.w = -__expf(al.w);

    // carry: hin[c] via the serial recurrence h = hloc[cp-1] + exp(A*D[cp-1])*h
    float4 hi = make_float4(0.f, 0.f, 0.f, 0.f);
    for (int cp = 1; cp <= c; cp++) {
        const float4 hl = *(const float4*)(hloc + ((size_t)((cp - 1) * DI + d)) * S + s0);
        const float Dc = Dchunk[(cp - 1) * DI + d];
        hi.x = hl.x + __expf(A.x * Dc) * hi.x;
        hi.y = hl.y + __expf(A.y * Dc) * hi.y;
        hi.z = hl.z + __expf(A.z * Dc) * hi.z;
        hi.w = hl.w + __expf(A.w * Dc) * hi.w;
    }

    float cd = 0.0f;
    float pr[8];

    for (int tb = 0; tb < TCv; tb += 8) {
#pragma unroll
        for (int i = 0; i < 8; i++) {
            const int tt = t0 + tb + i;
            const float dd = delta[tt * DI + d];
            cd += dd;
            const float4 C = *(const float4*)(Cm + tt * S + s0);
            const float fx = hi.x * __expf(cd * A.x);
            const float fy = hi.y * __expf(cd * A.y);
            const float fz = hi.z * __expf(cd * A.z);
            const float fw = hi.w * __expf(cd * A.w);
            pr[i] = fx * C.x + fy * C.y + fz * C.z + fw * C.w;
        }
#pragma unroll
        for (int i = 0; i < 8; i++) {
#pragma unroll
            for (int m = 1; m < 64; m <<= 1) pr[i] += __shfl_xor(pr[i], m, 64);
        }
        if (ln == 0) {
#pragma unroll
            for (int i = 0; i < 8; i++) {
                const int tt = t0 + tb + i;
                y[tt * DI + d] += pr[i];
            }
        }
    }
}

// ---------------------------------------------------------------------------
// K4: yf = (y + xs*Dp)*silu(zg); feat = yf @ W_outT; 3 head matmuls -> d_out
// ---------------------------------------------------------------------------
__global__ __launch_bounds__(256) void k4_heads(
    const float* __restrict__ y, const float* __restrict__ xs,
    const float* __restrict__ Dp, const float* __restrict__ zg,
    const float* __restrict__ W_outT,
    const float* __restrict__ We, const float* __restrict__ be,
    const float* __restrict__ Wa, const float* __restrict__ ba,
    const float* __restrict__ Wq, const float* __restrict__ bq,
    float* __restrict__ out)
{
    const int bb = blockIdx.x * 2;
    const int tid = threadIdx.x;
    __shared__ float yf[2][DI];
    __shared__ float feat[2][E];

    for (int idx = tid; idx < 2 * DI; idx += 256) {
        const int r = idx >> 8, c = idx & 255;
        const int b = bb + r;
        const float z = zg[b * DI + c];
        yf[r][c] = (y[b * DI + c] + xs[b * DI + c] * Dp[c]) * silu_f(z);
    }
    __syncthreads();

    {
        const int r = tid >> 7, e = tid & 127;
        float a = 0.0f;
#pragma unroll 8
        for (int dd = 0; dd < DI; dd++) a += yf[r][dd] * W_outT[dd * E + e];
        feat[r][e] = a;
    }
    __syncthreads();

    if (tid < 16) {
        const int r = tid >> 3, hd = tid & 7;
        const int b = bb + r;
        const float* wrow;
        float bias;
        int dst;
        if (hd == 0)      { wrow = We;                 bias = be[0];      dst = b; }
        else if (hd < 4)  { wrow = Wa + (hd - 1) * E;  bias = ba[hd - 1]; dst = 512 + b * 3 + (hd - 1); }
        else              { wrow = Wq + (hd - 4) * E;  bias = bq[hd - 4]; dst = 2048 + b * 4 + (hd - 4); }
        float a = bias;
#pragma unroll 4
        for (int e = 0; e < E; e++) a += feat[r][e] * wrow[e];
        out[dst] = a;
    }
}

// ---------------------------------------------------------------------------
template <int NCv>
static void launch_scan(const float* A_log, const float* delta, const float* xs,
                        const float* Bm, const float* Cm, float* y,
                        float* hloc, float* Dchunk, hipStream_t stream)
{
    k3a_local<NCv><<<dim3(64, NCv), 256, 0, stream>>>(A_log, delta, xs, Bm, Cm, y, hloc, Dchunk);
    k3c_fix<NCv><<<dim3(64, NCv - 1), 256, 0, stream>>>(A_log, delta, Cm, hloc, Dchunk, y);
}

extern "C" void kernel_launch(void* const* d_in, const int* in_sizes, int n_in,
                              void* d_out, int out_size, void* d_ws, size_t ws_size,
                              hipStream_t stream)
{
    const float* x        = (const float*)d_in[0];
    const float* conv_w   = (const float*)d_in[1];
    const float* conv_b   = (const float*)d_in[2];
    const float* lin_w    = (const float*)d_in[3];
    const float* lin_b    = (const float*)d_in[4];
    const float* W_in     = (const float*)d_in[5];
    const float* conv1d_w = (const float*)d_in[6];
    const float* conv1d_b = (const float*)d_in[7];
    const float* W_x      = (const float*)d_in[8];
    const float* W_dt     = (const float*)d_in[9];
    const float* b_dt     = (const float*)d_in[10];
    const float* A_log    = (const float*)d_in[11];
    const float* Dp       = (const float*)d_in[12];
    const float* W_out    = (const float*)d_in[13];
    const float* We       = (const float*)d_in[14];
    const float* be       = (const float*)d_in[15];
    const float* Wa       = (const float*)d_in[16];
    const float* ba       = (const float*)d_in[17];
    const float* Wq       = (const float*)d_in[18];
    const float* bq       = (const float*)d_in[19];
    float* out = (float*)d_out;

    float* ws = (float*)d_ws;
    float* u31    = ws;                    // 512*128
    float* xm     = u31    + 512 * 128;    // 512*256 each below
    float* zg     = xm     + 512 * 256;
    float* xs     = zg     + 512 * 256;
    float* delta  = xs     + 512 * 256;
    float* Bm     = delta  + 512 * 256;
    float* Cm     = Bm     + 512 * 256;
    float* y      = Cm     + 512 * 256;
    float* W_inT  = y      + 512 * 256;    // 128*512
    float* W_xT   = W_inT  + 128 * 512;    // 256*520
    float* W_dtT  = W_xT   + 256 * JWX;    // 8*256
    float* W_outT = W_dtT  + 8 * 256;      // 256*128
    float* c1wT   = W_outT + 256 * 128;    // 4*256
    float* tail   = c1wT   + 4 * 256;      // hloc / Dchunk

    const size_t base_floats = (size_t)(tail - ws);
    const size_t avail = ws_size / 4 - base_floats;

    kA_pre<<<539, 256, 0, stream>>>(x, conv_w, conv_b, lin_w, lin_b, u31,
                                    W_in, W_x, W_dt, W_out, conv1d_w,
                                    W_inT, W_xT, W_dtT, W_outT, c1wT);
    k2a_win<<<dim3(128, 8), 256, 0, stream>>>(u31, W_inT, xm, zg);
    k2b_conv_wx<<<dim3(128, 9), 256, 0, stream>>>(xm, c1wT, conv1d_b, W_xT, W_dtT, b_dt,
                                                  xs, delta, Bm, Cm);

    // need: NC*DI*S + NC*DI floats for hloc + Dchunk
    if (avail >= (size_t)32 * DI * S + 32 * DI) {
        float* hloc = tail;
        float* Dch  = hloc + (size_t)32 * DI * S;
        launch_scan<32>(A_log, delta, xs, Bm, Cm, y, hloc, Dch, stream);
    } else if (avail >= (size_t)16 * DI * S + 16 * DI) {
        float* hloc = tail;
        float* Dch  = hloc + (size_t)16 * DI * S;
        launch_scan<16>(A_log, delta, xs, Bm, Cm, y, hloc, Dch, stream);
    } else {
        float* hloc = tail;
        float* Dch  = hloc + (size_t)8 * DI * S;
        launch_scan<8>(A_log, delta, xs, Bm, Cm, y, hloc, Dch, stream);
    }

    k4_heads<<<256, 256, 0, stream>>>(y, xs, Dp, zg, W_outT, We, be, Wa, ba, Wq, bq, out);
}